// Round 15
// baseline (174.899 us; speedup 1.0000x reference)
//
#include <hip/hip_runtime.h>
#include <cmath>

// Problem constants (B=4096, D=256, P=100, K=10, n=2B=8192, T=0.2)
#define BB   4096
#define DD   256
#define NN   8192
#define PP   100
#define KK   10

typedef float f32x16 __attribute__((ext_vector_type(16)));
typedef long  lx2    __attribute__((ext_vector_type(2)));

// ---------------- workspace layout (bytes) ----------------
constexpr size_t OFF_DPART = 0;        // 64 double
constexpr size_t OFF_PPART = 512;      // 64 double
constexpr size_t OFF_CNT   = 1536;     // 100 int
constexpr size_t OFF_MU    = 2048;     // 100 f32
constexpr size_t OFF_SD    = 2560;     // 100 f32
constexpr size_t OFF_RWN   = 3072;     // 10000 f32 -> 43072
constexpr size_t OFF_PI    = 43072;    // 8192 int (sorted pos -> orig)
constexpr size_t OFF_INVP  = 75840;    // 8192 int (orig -> sorted pos)
constexpr size_t OFF_HQP   = 108608;   // 8192 int (class at sorted pos)
constexpr size_t OFF_CTABT = 141376;   // 100*8192 f32 transposed -> 3418176 (16B aligned)
constexpr size_t OFF_G     = 3418176;  // 8192*256 fp8 pair-packed (2 MB), 16B aligned

// Pair-packed fp8 G layout for mfma_f32_32x32x16_fp8_fp8 (byte addr):
// element (row p, k) at (p>>5)*8192 + (k>>5)*1024 + (((k>>3)&1)*32 + (p&31))*16
//                     + ((k>>4)&1)*8 + (k&7)
// => lane l's fragments for kc=2q,2q+1 are the contiguous 16 B at
//    (p>>5)*8192 + q*1024 + l*16   (low 8 B: kc=2q, high 8 B: kc=2q+1)

// ------ prep (1 block): zero accs, LDS histogram, scan, full counting sort ------
__global__ __launch_bounds__(1024) void prep_kernel(
    const int* __restrict__ hq, int* __restrict__ cnt,
    int* __restrict__ pi, int* __restrict__ invp, int* __restrict__ hqp,
    double* __restrict__ dpart, double* __restrict__ ppart) {
    __shared__ int h[16][PP];
    __shared__ int cur[PP];
    const int t = threadIdx.x;   // 1024
    const int wv = t >> 6;
    h[t & 15][t >> 4] = 0;       // zero 16x100 = 1600 slots in 2 passes
    if (t < 576) h[(t + 1024) & 15][(t + 1024) >> 4] = 0;
    if (t < 64) { dpart[t] = 0.0; ppart[t] = 0.0; }
    __syncthreads();
#pragma unroll
    for (int r = 0; r < 8; ++r) atomicAdd(&h[wv][hq[r * 1024 + t]], 1);
    __syncthreads();
    if (t < PP) {
        int s = 0;
#pragma unroll
        for (int w = 0; w < 16; ++w) s += h[w][t];
        cnt[t] = s;
        h[0][t] = s;
    }
    __syncthreads();
    if (t == 0) {
        int run = 0;
        for (int c = 0; c < PP; ++c) { cur[c] = run; run += h[0][c]; }
    }
    __syncthreads();
#pragma unroll
    for (int r = 0; r < 8; ++r) {
        const int i = r * 1024 + t;
        const int c = hq[i];
        const int d = atomicAdd(&cur[c], 1);   // LDS atomic: fast
        pi[d] = i;
        hqp[d] = c;
        invp[i] = d;
    }
}

// ---- merged: blocks 0..1023 normalize (wave/sample); blocks 1024..1123 protopd ----
__global__ __launch_bounds__(256) void norm_protopd_kernel(
    const float* __restrict__ x, const float* __restrict__ xa,
    const float* __restrict__ pw, const int* __restrict__ invp,
    const int* __restrict__ cnt, char* __restrict__ Gpb, double* __restrict__ ppart,
    float* __restrict__ rwn, float* __restrict__ mu, float* __restrict__ sd) {
    const int blk = blockIdx.x;
    const int t = threadIdx.x;
    if (blk < 1024) {
        // ---- normalize role: wave per sample, barrier-free ----
        const int wv = t >> 6, lane = t & 63;
        const int i = blk * 4 + wv;            // sample 0..4095
        const float4 v1 = *(const float4*)(x  + (size_t)i * DD + lane * 4);
        const float4 v2 = *(const float4*)(xa + (size_t)i * DD + lane * 4);
        float a = v1.x * v1.x + v1.y * v1.y + v1.z * v1.z + v1.w * v1.w;
        float b = v2.x * v2.x + v2.y * v2.y + v2.z * v2.z + v2.w * v2.w;
        float c = v1.x * v2.x + v1.y * v2.y + v1.z * v2.z + v1.w * v2.w;
#pragma unroll
        for (int off = 32; off > 0; off >>= 1) {
            a += __shfl_xor(a, off);
            b += __shfl_xor(b, off);
            c += __shfl_xor(c, off);
        }
        const float d1 = fmaxf(sqrtf(a), 1e-12f), i1 = 1.0f / d1;
        const float d2 = fmaxf(sqrtf(b), 1e-12f), i2 = 1.0f / d2;
        const int p1 = invp[i];
        const int p2 = invp[i + BB];
        int w1 = __builtin_amdgcn_cvt_pk_fp8_f32(v1.x * i1, v1.y * i1, 0, false);
        w1 = __builtin_amdgcn_cvt_pk_fp8_f32(v1.z * i1, v1.w * i1, w1, true);
        int w2 = __builtin_amdgcn_cvt_pk_fp8_f32(v2.x * i2, v2.y * i2, 0, false);
        w2 = __builtin_amdgcn_cvt_pk_fp8_f32(v2.z * i2, v2.w * i2, w2, true);
        // lane l holds k0 = 4l: q=k0>>5, halfsel=(k0>>3)&1, pairsel=(k0>>4)&1
        const int q = lane >> 3, halfsel = (lane >> 1) & 1, pairsel = (lane >> 2) & 1;
        const int bo = pairsel * 8 + 4 * (lane & 1);
        const size_t a1 = (size_t)((p1 >> 5) * 8192 + q * 1024 +
                                   (halfsel * 32 + (p1 & 31)) * 16 + bo);
        const size_t a2 = (size_t)((p2 >> 5) * 8192 + q * 1024 +
                                   (halfsel * 32 + (p2 & 31)) * 16 + bo);
        *(int*)(Gpb + a1) = w1;
        *(int*)(Gpb + a2) = w2;
        if (lane == 0) atomicAdd(&ppart[i & 63], (double)(c * i1 * i2));
    } else {
        // ---- protopd role: proto-norm row a + pd row + per-class stats ----
        const int a = blk - 1024;   // 0..99
        __shared__ alignas(16) float wa[DD];
        __shared__ float pdrow[PP];
        __shared__ float r4[4];
        float av = pw[(size_t)a * DD + t];
        float ss = av * av;
#pragma unroll
        for (int off = 32; off > 0; off >>= 1) ss += __shfl_down(ss, off);
        if ((t & 63) == 0) r4[t >> 6] = ss;
        __syncthreads();
        const float na = fmaxf(sqrtf(r4[0] + r4[1] + r4[2] + r4[3]), 1e-12f);
        wa[t] = av / na;
        __syncthreads();
        if (t < PP) {
            const float4* wc = (const float4*)(pw + (size_t)t * DD);
            float dot = 0.f, nb = 0.f;
#pragma unroll 4
            for (int k = 0; k < 64; ++k) {
                const float4 w = wc[k];
                const float4 u = *(const float4*)(wa + 4 * k);
                dot += u.x * w.x + u.y * w.y + u.z * w.z + u.w * w.w;
                nb += w.x * w.x + w.y * w.y + w.z * w.z + w.w * w.w;
            }
            pdrow[t] = 1.0f - dot / fmaxf(sqrtf(nb), 1e-12f);
        }
        __syncthreads();
        if (t < 64) {
            const int lane = t;
            float vmin = 0.f, vmax = 0.f;  // eye-zero always in multiset
            for (int b = lane; b < PP; b += 64) {
                int cc = cnt[b] - (b == a ? 1 : 0);
                if (cc > 0) {
                    float v = pdrow[b];
                    vmin = fminf(vmin, v);
                    vmax = fmaxf(vmax, v);
                }
            }
#pragma unroll
            for (int off = 32; off > 0; off >>= 1) {
                vmin = fminf(vmin, __shfl_xor(vmin, off));
                vmax = fmaxf(vmax, __shfl_xor(vmax, off));
            }
            const float den = vmax - vmin;
            const float inv = (den > 0.f) ? 1.f / den : 0.f;
            double s1 = 0.0, s2 = 0.0;
            for (int b = lane; b < PP; b += 64) {
                float v = (pdrow[b] - vmin) * inv;
                rwn[a * PP + b] = v;
                int cc = cnt[b] - (b == a ? 1 : 0);
                if (cc > 0) { double dv = v; s1 += cc * dv; s2 += cc * dv * dv; }
            }
            if (lane == 0) { double v0 = (0.0 - (double)vmin) * inv; s1 += v0; s2 += v0 * v0; }
#pragma unroll
            for (int off = 32; off > 0; off >>= 1) {
                s1 += __shfl_xor(s1, off);
                s2 += __shfl_xor(s2, off);
            }
            if (lane == 0) {
                double m = s1 / (double)NN;
                double var = (s2 - (double)NN * m * m) / (double)(NN - 1);
                mu[a] = (float)m;
                sd[a] = (float)sqrt(fmax(var, 0.0));
            }
        }
    }
}

// ---- CtabT[c][p] = (c in neg_q[pi[p]]) ? exp((rwn[hqp[p]][c]-mu[c])^2/(2 sd[c]^2)) : 0
__global__ __launch_bounds__(256) void ctab_kernel(
    const int* __restrict__ pi, const int* __restrict__ hqp, const int* __restrict__ nq,
    const float* __restrict__ rwn, const float* __restrict__ mu, const float* __restrict__ sd,
    float* __restrict__ CtabT) {
    const int p0 = blockIdx.x * 128;
    const int t = threadIdx.x;
    __shared__ unsigned long long bits[128][2];
    __shared__ int cls[128];
    __shared__ float smu[PP], ssd[PP];
    if (t < 128) {
        const int p = p0 + t;
        const int* row = nq + (size_t)pi[p] * KK;
        unsigned long long b0 = 0, b1 = 0;
#pragma unroll
        for (int k = 0; k < KK; ++k) {
            int c = row[k];
            if (c < 64) b0 |= 1ull << c; else b1 |= 1ull << (c - 64);
        }
        bits[t][0] = b0;
        bits[t][1] = b1;
        cls[t] = hqp[p];
    }
    if (t < PP) { smu[t] = mu[t]; ssd[t] = sd[t]; }
    __syncthreads();
    for (int idx = t; idx < 128 * PP; idx += 256) {
        const int c = idx >> 7;
        const int pl = idx & 127;
        const bool m = (c < 64) ? ((bits[pl][0] >> c) & 1) : ((bits[pl][1] >> (c - 64)) & 1);
        float v = 0.f;
        if (m) {
            float d = rwn[cls[pl] * PP + c] - smu[c];
            float s = ssd[c];
            v = expf(d * d / (2.0f * s * s));
        }
        CtabT[(size_t)c * NN + p0 + pl] = v;
    }
}

// ---------------- symmetric fused GEMM over upper-triangular blocks ----------------
// denom = sum_{p<q} exp(5*dot_pq) * (CtabT[cls q][p] + CtabT[cls p][q])
// Tiles 128x128 (64 block-cols), 2x2 waves of 64x64; kept: bi <= bj (2080 blocks).
// Per wave: 32 pair-loads -> 64 MFMAs (load:MFMA 0.5). XCD swizzle on bj mod 8:
// per-XCD count = 232 + 8*xcd (max 288), launch 8*288, excess blocks exit.
// NO fences anywhere (R10/R11 lesson). No LDS staging (R9 lesson).
__global__ __launch_bounds__(256) void sim_kernel(
    const char* __restrict__ Gpb, const int* __restrict__ hqp,
    const float* __restrict__ CtabT, double* __restrict__ dpart) {
    const int xcd = blockIdx.x & 7;
    int idx = blockIdx.x >> 3;               // 0..287
    int bj = -1, bi = 0;
#pragma unroll
    for (int q = 0; q < 8; ++q) {            // bj = xcd+8q (<= 63), bi = 0..bj
        const int bjq = xcd + 8 * q;
        const int c = bjq + 1;
        if (idx < c) { bj = bjq; bi = idx; break; }
        idx -= c;
    }
    if (bj < 0) return;                      // block-uniform early exit

    const int t = threadIdx.x;
    const int lane = t & 63;
    const int wv = t >> 6;
    const int i0w = bi * 128 + (wv >> 1) * 64;   // wave row base (64 rows)
    const int j0w = bj * 128 + (wv & 1) * 64;    // wave col base (64 cols)

    f32x16 acc[2][2] = {};

    const char* pa0 = Gpb + (size_t)(i0w >> 5) * 8192 + lane * 16;   // 8 pairs * 1024B
    const char* pa1 = pa0 + 8192;
    const char* pb0 = Gpb + (size_t)(j0w >> 5) * 8192 + lane * 16;
    const char* pb1 = pb0 + 8192;

#pragma unroll
    for (int q = 0; q < 8; ++q) {
        const lx2 a0 = *(const lx2*)(pa0 + q * 1024);
        const lx2 a1 = *(const lx2*)(pa1 + q * 1024);
        const lx2 b0 = *(const lx2*)(pb0 + q * 1024);
        const lx2 b1 = *(const lx2*)(pb1 + q * 1024);
        acc[0][0] = __builtin_amdgcn_mfma_f32_32x32x16_fp8_fp8(a0.x, b0.x, acc[0][0], 0, 0, 0);
        acc[0][1] = __builtin_amdgcn_mfma_f32_32x32x16_fp8_fp8(a0.x, b1.x, acc[0][1], 0, 0, 0);
        acc[1][0] = __builtin_amdgcn_mfma_f32_32x32x16_fp8_fp8(a1.x, b0.x, acc[1][0], 0, 0, 0);
        acc[1][1] = __builtin_amdgcn_mfma_f32_32x32x16_fp8_fp8(a1.x, b1.x, acc[1][1], 0, 0, 0);
        acc[0][0] = __builtin_amdgcn_mfma_f32_32x32x16_fp8_fp8(a0.y, b0.y, acc[0][0], 0, 0, 0);
        acc[0][1] = __builtin_amdgcn_mfma_f32_32x32x16_fp8_fp8(a0.y, b1.y, acc[0][1], 0, 0, 0);
        acc[1][0] = __builtin_amdgcn_mfma_f32_32x32x16_fp8_fp8(a1.y, b0.y, acc[1][0], 0, 0, 0);
        acc[1][1] = __builtin_amdgcn_mfma_f32_32x32x16_fp8_fp8(a1.y, b1.y, acc[1][1], 0, 0, 0);
    }

    // C/D layout (32x32): col = lane&31, row = (reg&3) + 8*(reg>>2) + 4*(lane>>5)
    const int cl = lane & 31, h = lane >> 5;
    float partial = 0.f;
#pragma unroll
    for (int ni = 0; ni < 2; ++ni) {
        const int col = j0w + ni * 32 + cl;
        const float* ctc = CtabT + (size_t)hqp[col] * NN;   // column-class row
#pragma unroll
        for (int mi = 0; mi < 2; ++mi) {
#pragma unroll
            for (int g = 0; g < 4; ++g) {
                const int rbase = i0w + mi * 32 + 8 * g + 4 * h;
                const float4 cf = *(const float4*)(ctc + rbase);    // 4 consecutive rows
                const float* f = (const float*)&cf;
#pragma unroll
                for (int r = 0; r < 4; ++r) {
                    const int row = rbase + r;
                    const float c2 = (CtabT + (size_t)hqp[row] * NN)[col];  // coalesced
                    const float e = __expf(acc[mi][ni][4 * g + r] * 5.0f);
                    partial += (row < col) ? e * (f[r] + c2) : 0.f;
                }
            }
        }
    }
#pragma unroll
    for (int off = 32; off > 0; off >>= 1) partial += __shfl_down(partial, off);
    __shared__ float wsum[4];
    if (lane == 0) wsum[wv] = partial;
    __syncthreads();
    if (t == 0)
        atomicAdd(&dpart[blockIdx.x & 63], (double)(wsum[0] + wsum[1] + wsum[2] + wsum[3]));
}

// ---------------- finalize ----------------
__global__ void finalize_kernel(const double* __restrict__ dpart,
                                const double* __restrict__ ppart, float* __restrict__ out) {
    const int lane = threadIdx.x;  // 64
    double d = dpart[lane], p = ppart[lane];
#pragma unroll
    for (int off = 32; off > 0; off >>= 1) {
        d += __shfl_down(d, off);
        p += __shfl_down(p, off);
    }
    if (lane == 0) out[0] = (float)(log(d) - p * (5.0 / 4096.0));
}

extern "C" void kernel_launch(void* const* d_in, const int* in_sizes, int n_in,
                              void* d_out, int out_size, void* d_ws, size_t ws_size,
                              hipStream_t stream) {
    const float* x  = (const float*)d_in[0];
    const float* xa = (const float*)d_in[1];
    const float* pw = (const float*)d_in[2];
    const int* hq   = (const int*)d_in[3];
    const int* nq   = (const int*)d_in[4];
    float* out      = (float*)d_out;

    char* ws = (char*)d_ws;
    double* dpart = (double*)(ws + OFF_DPART);
    double* ppart = (double*)(ws + OFF_PPART);
    int* cnt      = (int*)(ws + OFF_CNT);
    float* mu     = (float*)(ws + OFF_MU);
    float* sd     = (float*)(ws + OFF_SD);
    float* rwn    = (float*)(ws + OFF_RWN);
    int* pi       = (int*)(ws + OFF_PI);
    int* invp     = (int*)(ws + OFF_INVP);
    int* hqp      = (int*)(ws + OFF_HQP);
    float* CtabT  = (float*)(ws + OFF_CTABT);
    char* Gpb     = (char*)(ws + OFF_G);

    prep_kernel<<<1, 1024, 0, stream>>>(hq, cnt, pi, invp, hqp, dpart, ppart);
    norm_protopd_kernel<<<1124, 256, 0, stream>>>(x, xa, pw, invp, cnt, Gpb, ppart,
                                                  rwn, mu, sd);
    ctab_kernel<<<NN / 128, 256, 0, stream>>>(pi, hqp, nq, rwn, mu, sd, CtabT);
    sim_kernel<<<8 * 288, 256, 0, stream>>>(Gpb, hqp, CtabT, dpart);
    finalize_kernel<<<1, 64, 0, stream>>>(dpart, ppart, out);
}

// Round 16
// 158.107 us; speedup vs baseline: 1.1062x; 1.1062x over previous
//
#include <hip/hip_runtime.h>
#include <cmath>

// Problem constants (B=4096, D=256, P=100, K=10, n=2B=8192, T=0.2)
#define BB   4096
#define DD   256
#define NN   8192
#define PP   100
#define KK   10

typedef float f32x16 __attribute__((ext_vector_type(16)));
typedef long  lx2    __attribute__((ext_vector_type(2)));

// ---------------- workspace layout (bytes) ----------------
constexpr size_t OFF_DPART = 0;        // 64 double
constexpr size_t OFF_PPART = 512;      // 64 double
constexpr size_t OFF_CNT   = 1536;     // 100 int
constexpr size_t OFF_MU    = 2048;     // 100 f32
constexpr size_t OFF_SD    = 2560;     // 100 f32
constexpr size_t OFF_RWN   = 3072;     // 10000 f32 -> 43072
constexpr size_t OFF_PI    = 43072;    // 8192 int (sorted pos -> orig)
constexpr size_t OFF_INVP  = 75840;    // 8192 int (orig -> sorted pos)
constexpr size_t OFF_HQP   = 108608;   // 8192 int (class at sorted pos)
constexpr size_t OFF_CTABT = 141376;   // 100*8192 f32 transposed -> 3418176 (16B aligned)
constexpr size_t OFF_G     = 3418176;  // 8192*256 fp8 pair-packed (2 MB), 16B aligned

// Pair-packed fp8 G layout for mfma_f32_32x32x16_fp8_fp8 (byte addr):
// element (row p, k) at (p>>5)*8192 + (k>>5)*1024 + (((k>>3)&1)*32 + (p&31))*16
//                     + ((k>>4)&1)*8 + (k&7)
// => lane l's fragments for kc=2q,2q+1 are the contiguous 16 B at
//    (p>>5)*8192 + q*1024 + l*16   (low 8 B: kc=2q, high 8 B: kc=2q+1)

// ------ prep (1 block): zero accs, LDS histogram, scan, full counting sort ------
__global__ __launch_bounds__(1024) void prep_kernel(
    const int* __restrict__ hq, int* __restrict__ cnt,
    int* __restrict__ pi, int* __restrict__ invp, int* __restrict__ hqp,
    double* __restrict__ dpart, double* __restrict__ ppart) {
    __shared__ int h[16][PP];
    __shared__ int cur[PP];
    const int t = threadIdx.x;   // 1024
    const int wv = t >> 6;
    h[t & 15][t >> 4] = 0;       // zero 16x100 = 1600 slots in 2 passes
    if (t < 576) h[(t + 1024) & 15][(t + 1024) >> 4] = 0;
    if (t < 64) { dpart[t] = 0.0; ppart[t] = 0.0; }
    __syncthreads();
#pragma unroll
    for (int r = 0; r < 8; ++r) atomicAdd(&h[wv][hq[r * 1024 + t]], 1);
    __syncthreads();
    if (t < PP) {
        int s = 0;
#pragma unroll
        for (int w = 0; w < 16; ++w) s += h[w][t];
        cnt[t] = s;
        h[0][t] = s;
    }
    __syncthreads();
    if (t == 0) {
        int run = 0;
        for (int c = 0; c < PP; ++c) { cur[c] = run; run += h[0][c]; }
    }
    __syncthreads();
#pragma unroll
    for (int r = 0; r < 8; ++r) {
        const int i = r * 1024 + t;
        const int c = hq[i];
        const int d = atomicAdd(&cur[c], 1);   // LDS atomic: fast
        pi[d] = i;
        hqp[d] = c;
        invp[i] = d;
    }
}

// ---- merged: blocks 0..1023 normalize (wave/sample); blocks 1024..1123 protopd ----
__global__ __launch_bounds__(256) void norm_protopd_kernel(
    const float* __restrict__ x, const float* __restrict__ xa,
    const float* __restrict__ pw, const int* __restrict__ invp,
    const int* __restrict__ cnt, char* __restrict__ Gpb, double* __restrict__ ppart,
    float* __restrict__ rwn, float* __restrict__ mu, float* __restrict__ sd) {
    const int blk = blockIdx.x;
    const int t = threadIdx.x;
    if (blk < 1024) {
        // ---- normalize role: wave per sample, barrier-free ----
        const int wv = t >> 6, lane = t & 63;
        const int i = blk * 4 + wv;            // sample 0..4095
        const float4 v1 = *(const float4*)(x  + (size_t)i * DD + lane * 4);
        const float4 v2 = *(const float4*)(xa + (size_t)i * DD + lane * 4);
        float a = v1.x * v1.x + v1.y * v1.y + v1.z * v1.z + v1.w * v1.w;
        float b = v2.x * v2.x + v2.y * v2.y + v2.z * v2.z + v2.w * v2.w;
        float c = v1.x * v2.x + v1.y * v2.y + v1.z * v2.z + v1.w * v2.w;
#pragma unroll
        for (int off = 32; off > 0; off >>= 1) {
            a += __shfl_xor(a, off);
            b += __shfl_xor(b, off);
            c += __shfl_xor(c, off);
        }
        const float d1 = fmaxf(sqrtf(a), 1e-12f), i1 = 1.0f / d1;
        const float d2 = fmaxf(sqrtf(b), 1e-12f), i2 = 1.0f / d2;
        const int p1 = invp[i];
        const int p2 = invp[i + BB];
        int w1 = __builtin_amdgcn_cvt_pk_fp8_f32(v1.x * i1, v1.y * i1, 0, false);
        w1 = __builtin_amdgcn_cvt_pk_fp8_f32(v1.z * i1, v1.w * i1, w1, true);
        int w2 = __builtin_amdgcn_cvt_pk_fp8_f32(v2.x * i2, v2.y * i2, 0, false);
        w2 = __builtin_amdgcn_cvt_pk_fp8_f32(v2.z * i2, v2.w * i2, w2, true);
        // lane l holds k0 = 4l: q=k0>>5, halfsel=(k0>>3)&1, pairsel=(k0>>4)&1
        const int q = lane >> 3, halfsel = (lane >> 1) & 1, pairsel = (lane >> 2) & 1;
        const int bo = pairsel * 8 + 4 * (lane & 1);
        const size_t a1 = (size_t)((p1 >> 5) * 8192 + q * 1024 +
                                   (halfsel * 32 + (p1 & 31)) * 16 + bo);
        const size_t a2 = (size_t)((p2 >> 5) * 8192 + q * 1024 +
                                   (halfsel * 32 + (p2 & 31)) * 16 + bo);
        *(int*)(Gpb + a1) = w1;
        *(int*)(Gpb + a2) = w2;
        if (lane == 0) atomicAdd(&ppart[i & 63], (double)(c * i1 * i2));
    } else {
        // ---- protopd role: proto-norm row a + pd row + per-class stats ----
        const int a = blk - 1024;   // 0..99
        __shared__ alignas(16) float wa[DD];
        __shared__ float pdrow[PP];
        __shared__ float r4[4];
        float av = pw[(size_t)a * DD + t];
        float ss = av * av;
#pragma unroll
        for (int off = 32; off > 0; off >>= 1) ss += __shfl_down(ss, off);
        if ((t & 63) == 0) r4[t >> 6] = ss;
        __syncthreads();
        const float na = fmaxf(sqrtf(r4[0] + r4[1] + r4[2] + r4[3]), 1e-12f);
        wa[t] = av / na;
        __syncthreads();
        if (t < PP) {
            const float4* wc = (const float4*)(pw + (size_t)t * DD);
            float dot = 0.f, nb = 0.f;
#pragma unroll 4
            for (int k = 0; k < 64; ++k) {
                const float4 w = wc[k];
                const float4 u = *(const float4*)(wa + 4 * k);
                dot += u.x * w.x + u.y * w.y + u.z * w.z + u.w * w.w;
                nb += w.x * w.x + w.y * w.y + w.z * w.z + w.w * w.w;
            }
            pdrow[t] = 1.0f - dot / fmaxf(sqrtf(nb), 1e-12f);
        }
        __syncthreads();
        if (t < 64) {
            const int lane = t;
            float vmin = 0.f, vmax = 0.f;  // eye-zero always in multiset
            for (int b = lane; b < PP; b += 64) {
                int cc = cnt[b] - (b == a ? 1 : 0);
                if (cc > 0) {
                    float v = pdrow[b];
                    vmin = fminf(vmin, v);
                    vmax = fmaxf(vmax, v);
                }
            }
#pragma unroll
            for (int off = 32; off > 0; off >>= 1) {
                vmin = fminf(vmin, __shfl_xor(vmin, off));
                vmax = fmaxf(vmax, __shfl_xor(vmax, off));
            }
            const float den = vmax - vmin;
            const float inv = (den > 0.f) ? 1.f / den : 0.f;
            double s1 = 0.0, s2 = 0.0;
            for (int b = lane; b < PP; b += 64) {
                float v = (pdrow[b] - vmin) * inv;
                rwn[a * PP + b] = v;
                int cc = cnt[b] - (b == a ? 1 : 0);
                if (cc > 0) { double dv = v; s1 += cc * dv; s2 += cc * dv * dv; }
            }
            if (lane == 0) { double v0 = (0.0 - (double)vmin) * inv; s1 += v0; s2 += v0 * v0; }
#pragma unroll
            for (int off = 32; off > 0; off >>= 1) {
                s1 += __shfl_xor(s1, off);
                s2 += __shfl_xor(s2, off);
            }
            if (lane == 0) {
                double m = s1 / (double)NN;
                double var = (s2 - (double)NN * m * m) / (double)(NN - 1);
                mu[a] = (float)m;
                sd[a] = (float)sqrt(fmax(var, 0.0));
            }
        }
    }
}

// ---- CtabT[c][p] = (c in neg_q[pi[p]]) ? exp((rwn[hqp[p]][c]-mu[c])^2/(2 sd[c]^2)) : 0
__global__ __launch_bounds__(256) void ctab_kernel(
    const int* __restrict__ pi, const int* __restrict__ hqp, const int* __restrict__ nq,
    const float* __restrict__ rwn, const float* __restrict__ mu, const float* __restrict__ sd,
    float* __restrict__ CtabT) {
    const int p0 = blockIdx.x * 128;
    const int t = threadIdx.x;
    __shared__ unsigned long long bits[128][2];
    __shared__ int cls[128];
    __shared__ float smu[PP], ssd[PP];
    if (t < 128) {
        const int p = p0 + t;
        const int* row = nq + (size_t)pi[p] * KK;
        unsigned long long b0 = 0, b1 = 0;
#pragma unroll
        for (int k = 0; k < KK; ++k) {
            int c = row[k];
            if (c < 64) b0 |= 1ull << c; else b1 |= 1ull << (c - 64);
        }
        bits[t][0] = b0;
        bits[t][1] = b1;
        cls[t] = hqp[p];
    }
    if (t < PP) { smu[t] = mu[t]; ssd[t] = sd[t]; }
    __syncthreads();
    for (int idx = t; idx < 128 * PP; idx += 256) {
        const int c = idx >> 7;
        const int pl = idx & 127;
        const bool m = (c < 64) ? ((bits[pl][0] >> c) & 1) : ((bits[pl][1] >> (c - 64)) & 1);
        float v = 0.f;
        if (m) {
            float d = rwn[cls[pl] * PP + c] - smu[c];
            float s = ssd[c];
            v = expf(d * d / (2.0f * s * s));
        }
        CtabT[(size_t)c * NN + p0 + pl] = v;
    }
}

// ---------------- symmetric fused GEMM over upper-triangular blocks ----------------
// denom = sum_{p<q} exp(5*dot_pq) * (CtabT[cls q][p] + CtabT[cls p][q])
// Tiles 128(i) x 64(j); kept: bj >= 2*bi (4160 blocks).
// XCD swizzle: xcd = L&7 owns columns bj = xcd (mod 8).
// K-loop: 24 dwordx4 loads (pair-packed) instead of 48 dwordx2 -> half the
// outstanding-load slots for the same bytes. NO fences (R10/R11 lesson).
// R13-optimal: both tile-size directions from here were measured and regress
// (64x64: R12 53us; 128x128: R15 62us — reg pressure kills concurrency).
__global__ __launch_bounds__(256) void sim_kernel(
    const char* __restrict__ Gpb, const int* __restrict__ hqp,
    const float* __restrict__ CtabT, double* __restrict__ dpart) {
    const int xcd = blockIdx.x & 7;
    int idx = blockIdx.x >> 3;               // 0..543
    if (idx >= 496 + (xcd >> 1) * 16) return;  // block-uniform early exit
    int bj = 0, bi = 0;
#pragma unroll
    for (int q = 0; q < 16; ++q) {           // invert per-XCD triangular enumeration
        const int bjq = xcd + 8 * q;
        const int c = (bjq >> 1) + 1;
        if (idx < c) { bj = bjq; bi = idx; break; }
        idx -= c;
    }

    const int t = threadIdx.x;
    const int lane = t & 63;
    const int wv = t >> 6;
    const int i0w = bi * 128 + wv * 32;   // this wave's 32-row group base
    const int j0 = bj * 64;

    f32x16 acc[2] = {};

    const char* pa  = Gpb + (size_t)(i0w >> 5) * 8192 + lane * 16;   // 8 pairs * 1024B
    const char* pb0 = Gpb + (size_t)(j0 >> 5) * 8192 + lane * 16;
    const char* pb1 = pb0 + 8192;

#pragma unroll
    for (int q = 0; q < 8; ++q) {
        const lx2 a  = *(const lx2*)(pa  + q * 1024);
        const lx2 b0 = *(const lx2*)(pb0 + q * 1024);
        const lx2 b1 = *(const lx2*)(pb1 + q * 1024);
        acc[0] = __builtin_amdgcn_mfma_f32_32x32x16_fp8_fp8(a.x, b0.x, acc[0], 0, 0, 0);
        acc[1] = __builtin_amdgcn_mfma_f32_32x32x16_fp8_fp8(a.x, b1.x, acc[1], 0, 0, 0);
        acc[0] = __builtin_amdgcn_mfma_f32_32x32x16_fp8_fp8(a.y, b0.y, acc[0], 0, 0, 0);
        acc[1] = __builtin_amdgcn_mfma_f32_32x32x16_fp8_fp8(a.y, b1.y, acc[1], 0, 0, 0);
    }

    // C/D layout (32x32): col = lane&31, row = (reg&3) + 8*(reg>>2) + 4*(lane>>5)
    const int cl = lane & 31, h = lane >> 5;
    const int col0 = j0 + cl;
    const int col1 = j0 + 32 + cl;
    const float* ct0 = CtabT + (size_t)hqp[col0] * NN;   // coef by column class
    const float* ct1 = CtabT + (size_t)hqp[col1] * NN;
    float partial = 0.f;
#pragma unroll
    for (int g = 0; g < 4; ++g) {
        const int rbase = i0w + 8 * g + 4 * h;
        const float4 cf0 = *(const float4*)(ct0 + rbase);   // C[row][cls col0]
        const float4 cf1 = *(const float4*)(ct1 + rbase);   // C[row][cls col1]
        const float* f0 = (const float*)&cf0;
        const float* f1 = (const float*)&cf1;
#pragma unroll
        for (int r = 0; r < 4; ++r) {
            const int row = rbase + r;
            const float* ctr = CtabT + (size_t)hqp[row] * NN;  // half-wave uniform
            const float c20 = ctr[col0];                        // coalesced over cl
            const float c21 = ctr[col1];
            const float e0 = __expf(acc[0][4 * g + r] * 5.0f);
            const float e1 = __expf(acc[1][4 * g + r] * 5.0f);
            partial += (row < col0) ? e0 * (f0[r] + c20) : 0.f;
            partial += (row < col1) ? e1 * (f1[r] + c21) : 0.f;
        }
    }
#pragma unroll
    for (int off = 32; off > 0; off >>= 1) partial += __shfl_down(partial, off);
    __shared__ float wsum[4];
    if (lane == 0) wsum[wv] = partial;
    __syncthreads();
    if (t == 0)
        atomicAdd(&dpart[blockIdx.x & 63], (double)(wsum[0] + wsum[1] + wsum[2] + wsum[3]));
}

// ---------------- finalize ----------------
__global__ void finalize_kernel(const double* __restrict__ dpart,
                                const double* __restrict__ ppart, float* __restrict__ out) {
    const int lane = threadIdx.x;  // 64
    double d = dpart[lane], p = ppart[lane];
#pragma unroll
    for (int off = 32; off > 0; off >>= 1) {
        d += __shfl_down(d, off);
        p += __shfl_down(p, off);
    }
    if (lane == 0) out[0] = (float)(log(d) - p * (5.0 / 4096.0));
}

extern "C" void kernel_launch(void* const* d_in, const int* in_sizes, int n_in,
                              void* d_out, int out_size, void* d_ws, size_t ws_size,
                              hipStream_t stream) {
    const float* x  = (const float*)d_in[0];
    const float* xa = (const float*)d_in[1];
    const float* pw = (const float*)d_in[2];
    const int* hq   = (const int*)d_in[3];
    const int* nq   = (const int*)d_in[4];
    float* out      = (float*)d_out;

    char* ws = (char*)d_ws;
    double* dpart = (double*)(ws + OFF_DPART);
    double* ppart = (double*)(ws + OFF_PPART);
    int* cnt      = (int*)(ws + OFF_CNT);
    float* mu     = (float*)(ws + OFF_MU);
    float* sd     = (float*)(ws + OFF_SD);
    float* rwn    = (float*)(ws + OFF_RWN);
    int* pi       = (int*)(ws + OFF_PI);
    int* invp     = (int*)(ws + OFF_INVP);
    int* hqp      = (int*)(ws + OFF_HQP);
    float* CtabT  = (float*)(ws + OFF_CTABT);
    char* Gpb     = (char*)(ws + OFF_G);

    prep_kernel<<<1, 1024, 0, stream>>>(hq, cnt, pi, invp, hqp, dpart, ppart);
    norm_protopd_kernel<<<1124, 256, 0, stream>>>(x, xa, pw, invp, cnt, Gpb, ppart,
                                                  rwn, mu, sd);
    ctab_kernel<<<NN / 128, 256, 0, stream>>>(pi, hqp, nq, rwn, mu, sd, CtabT);
    sim_kernel<<<8 * 544, 256, 0, stream>>>(Gpb, hqp, CtabT, dpart);
    finalize_kernel<<<1, 64, 0, stream>>>(dpart, ppart, out);
}